// Round 1
// baseline (2496.362 us; speedup 1.0000x reference)
//
#include <hip/hip_runtime.h>

// Problem constants: B=8, S=4096, D=2048
#define N_TOK   32768L
#define DMODEL  2048L
#define E1      6144L
#define ROT     1024
#define SMASK   4095

typedef __attribute__((ext_vector_type(8))) _Float16 half8;
typedef __attribute__((ext_vector_type(4))) _Float16 half4;
typedef __attribute__((ext_vector_type(4))) float    floatx4;
typedef __attribute__((ext_vector_type(4))) float    float4v;

// -------- async global->LDS, 16B per lane. LDS dest must be wave-uniform
// base + lane*16 (m104/m108) — our layouts are lane-linear by construction.
__device__ inline void gld16(const void* g, void* l) {
  __builtin_amdgcn_global_load_lds(
      (const __attribute__((address_space(1))) unsigned int*)g,
      (__attribute__((address_space(3))) unsigned int*)l,
      16, 0, 0);
}

// ---------------------------------------------------------------- converts
__global__ __launch_bounds__(256) void k_f2h(const float* __restrict__ in,
                                             _Float16* __restrict__ out,
                                             long nElem) {
  long i = ((long)blockIdx.x * 256 + threadIdx.x) * 4;
  if (i + 3 < nElem) {
    float4v v = *(const float4v*)(in + i);
    half4 o;
    o[0] = (_Float16)v[0]; o[1] = (_Float16)v[1];
    o[2] = (_Float16)v[2]; o[3] = (_Float16)v[3];
    *(half4*)(out + i) = o;
  }
}

__global__ __launch_bounds__(256) void k_zero(float* __restrict__ p, int n) {
  int i = blockIdx.x * 256 + threadIdx.x;
  if (i < n) p[i] = 0.f;
}

// ---------------------------------------------------------------- GEMM1
// QKV[m][e] = sum_d Xh[m][d] * W1h[e][d] + b_in[e]   (both operands K-major)
__global__ __launch_bounds__(256) void k_gemm_qkv(
    const _Float16* __restrict__ Xh, const _Float16* __restrict__ W1h,
    const float* __restrict__ b_in, _Float16* __restrict__ QKV) {
  __shared__ _Float16 As[128 * 32];
  __shared__ _Float16 Bs[128 * 32];
  const int t    = threadIdx.x;
  const int w    = t >> 6;
  const int l    = t & 63;
  const int quad = l >> 4;
  const int ln   = l & 15;
  const int wm   = (w & 1) << 6;
  const int wn   = (w >> 1) << 6;
  const long mBase = (long)blockIdx.x * 128;
  const long eBase = (long)blockIdx.y * 128;
  const int r4 = t >> 2;          // 0..63 : row within 64-row half-tile
  const int c4 = (t & 3) << 3;    // 0,8,16,24 : 8-elem chunk within BK=32

  floatx4 acc[4][4];
  for (int i = 0; i < 4; i++)
    for (int j = 0; j < 4; j++) acc[i][j] = (floatx4){0.f, 0.f, 0.f, 0.f};

  for (int k0 = 0; k0 < (int)DMODEL; k0 += 32) {
    const _Float16* gA0 = Xh  + (mBase + r4) * DMODEL + k0 + c4;
    const _Float16* gB0 = W1h + (eBase + r4) * DMODEL + k0 + c4;
    gld16(gA0,                &As[t * 8]);
    gld16(gA0 + 64 * DMODEL,  &As[2048 + t * 8]);
    gld16(gB0,                &Bs[t * 8]);
    gld16(gB0 + 64 * DMODEL,  &Bs[2048 + t * 8]);
    __builtin_amdgcn_s_waitcnt(0);
    __syncthreads();

    half8 af[4], bf[4];
    for (int mt = 0; mt < 4; mt++)
      af[mt] = *(const half8*)&As[(wm + mt * 16 + ln) * 32 + quad * 8];
    for (int nt = 0; nt < 4; nt++)
      bf[nt] = *(const half8*)&Bs[(wn + nt * 16 + ln) * 32 + quad * 8];
    for (int mt = 0; mt < 4; mt++)
      for (int nt = 0; nt < 4; nt++)
        acc[mt][nt] = __builtin_amdgcn_mfma_f32_16x16x32_f16(
            af[mt], bf[nt], acc[mt][nt], 0, 0, 0);
    __syncthreads();
  }

  // C/D: col = lane&15, row = quad*4 + reg  (verified m89/m91)
  for (int nt = 0; nt < 4; nt++) {
    const long e  = eBase + wn + nt * 16 + ln;
    const float bi = b_in[e];
    for (int mt = 0; mt < 4; mt++) {
      const long m0 = mBase + wm + mt * 16 + quad * 4;
      for (int r = 0; r < 4; r++)
        QKV[(m0 + r) * E1 + e] = (_Float16)(acc[mt][nt][r] + bi);
    }
  }
}

// ---------------------------------------------------------------- reduce A
// A[b][d] = sum_s rope(K)[b,s,d]/||rope(K)[b,s,:]|| * V[b,s,d]
__global__ __launch_bounds__(256) void k_reduce_a(
    const _Float16* __restrict__ QKV, float* __restrict__ A) {
  const int t  = threadIdx.x;
  const int w  = t >> 6;
  const int l  = t & 63;
  const int wg = blockIdx.x * 4 + w;      // 0..2047
  const long row0 = (long)wg * 16;        // 16 rows per wave, same b
  const int b  = (int)(row0 >> 12);
  const int d0 = l * 32;                  // lane covers 32 contiguous d

  float invf[16];
  if (d0 < ROT) {
    for (int p = 0; p < 16; p++)
      invf[p] = (float)pow(10000.0, -(double)((d0 >> 1) + p) / 512.0);
  }

  float acc[32];
  for (int j = 0; j < 32; j++) acc[j] = 0.f;

  for (int i = 0; i < 16; i++) {
    const long n = row0 + i;
    const int  s = (int)(n & SMASK);
    const _Float16* Kr = QKV + n * E1 + DMODEL     + d0;
    const _Float16* Vr = QKV + n * E1 + 2 * DMODEL + d0;
    float kx[32];
    for (int c = 0; c < 4; c++) {
      half8 h = *(const half8*)(Kr + c * 8);
      for (int j = 0; j < 8; j++) kx[c * 8 + j] = (float)h[j];
    }
    if (d0 < ROT) {
      for (int p = 0; p < 16; p++) {
        float ang = (float)s * invf[p];
        double sd, cd; sincos((double)ang, &sd, &cd);
        float cs = (float)cd, sn = (float)sd;
        float x0 = kx[2 * p], x1 = kx[2 * p + 1];
        kx[2 * p]     = x0 * cs - x1 * sn;
        kx[2 * p + 1] = x1 * cs + x0 * sn;
      }
    }
    float ss = 0.f;
    for (int j = 0; j < 32; j++) ss += kx[j] * kx[j];
    for (int off = 32; off; off >>= 1) ss += __shfl_xor(ss, off);
    const float sc = 1.0f / fmaxf(sqrtf(ss), 1e-12f);
    for (int c = 0; c < 4; c++) {
      half8 h = *(const half8*)(Vr + c * 8);
      for (int j = 0; j < 8; j++)
        acc[c * 8 + j] += kx[c * 8 + j] * sc * (float)h[j];
    }
  }
  float* Ap = A + (long)b * DMODEL + d0;
  for (int j = 0; j < 32; j++) atomicAdd(&Ap[j], acc[j]);
}

// ---------------------------------------------------------------- Y1 = A ⊙ rope(Q), in place in Q slice
__global__ __launch_bounds__(256) void k_make_y1(
    _Float16* __restrict__ QKV, const float* __restrict__ A) {
  const long idx = (long)blockIdx.x * 256 + threadIdx.x;
  const long n   = idx >> 8;
  const int  c   = (int)(idx & 255);
  const int  d   = c * 8;
  const int  b   = (int)(n >> 12);
  const int  s   = (int)(n & SMASK);
  _Float16* Qp = QKV + n * E1 + d;
  half8 h = *(half8*)Qp;
  float x[8];
  for (int j = 0; j < 8; j++) x[j] = (float)h[j];
  if (d < ROT) {
    for (int p = 0; p < 4; p++) {
      const int j = (d >> 1) + p;
      float invf = (float)pow(10000.0, -(double)j / 512.0);
      float ang  = (float)s * invf;
      double sd, cd; sincos((double)ang, &sd, &cd);
      float cs = (float)cd, sn = (float)sd;
      float x0 = x[2 * p], x1 = x[2 * p + 1];
      x[2 * p]     = x0 * cs - x1 * sn;
      x[2 * p + 1] = x1 * cs + x0 * sn;
    }
  }
  const float* Ap = A + (long)b * DMODEL + d;
  for (int j = 0; j < 8; j++) x[j] *= Ap[j];
  half8 o;
  for (int j = 0; j < 8; j++) o[j] = (_Float16)x[j];
  *(half8*)Qp = o;
}

// ---------------------------------------------------------------- GEMM2
// Out[m][e] = sum_d Y1[m][d] * W2h[e][d] + b_out[e] + X[m][e]
__global__ __launch_bounds__(256) void k_gemm_out(
    const _Float16* __restrict__ Y1,   // QKV base, row stride E1, cols [0,2048)
    const _Float16* __restrict__ W2h,
    const float* __restrict__ b_out, const float* __restrict__ X,
    float* __restrict__ Out) {
  __shared__ _Float16 As[128 * 32];
  __shared__ _Float16 Bs[128 * 32];
  const int t    = threadIdx.x;
  const int w    = t >> 6;
  const int l    = t & 63;
  const int quad = l >> 4;
  const int ln   = l & 15;
  const int wm   = (w & 1) << 6;
  const int wn   = (w >> 1) << 6;
  const long mBase = (long)blockIdx.x * 128;
  const long eBase = (long)blockIdx.y * 128;
  const int r4 = t >> 2;
  const int c4 = (t & 3) << 3;

  floatx4 acc[4][4];
  for (int i = 0; i < 4; i++)
    for (int j = 0; j < 4; j++) acc[i][j] = (floatx4){0.f, 0.f, 0.f, 0.f};

  for (int k0 = 0; k0 < (int)DMODEL; k0 += 32) {
    const _Float16* gA0 = Y1  + (mBase + r4) * E1     + k0 + c4;
    const _Float16* gB0 = W2h + (eBase + r4) * DMODEL + k0 + c4;
    gld16(gA0,               &As[t * 8]);
    gld16(gA0 + 64 * E1,     &As[2048 + t * 8]);
    gld16(gB0,               &Bs[t * 8]);
    gld16(gB0 + 64 * DMODEL, &Bs[2048 + t * 8]);
    __builtin_amdgcn_s_waitcnt(0);
    __syncthreads();

    half8 af[4], bf[4];
    for (int mt = 0; mt < 4; mt++)
      af[mt] = *(const half8*)&As[(wm + mt * 16 + ln) * 32 + quad * 8];
    for (int nt = 0; nt < 4; nt++)
      bf[nt] = *(const half8*)&Bs[(wn + nt * 16 + ln) * 32 + quad * 8];
    for (int mt = 0; mt < 4; mt++)
      for (int nt = 0; nt < 4; nt++)
        acc[mt][nt] = __builtin_amdgcn_mfma_f32_16x16x32_f16(
            af[mt], bf[nt], acc[mt][nt], 0, 0, 0);
    __syncthreads();
  }

  for (int nt = 0; nt < 4; nt++) {
    const long e = eBase + wn + nt * 16 + ln;
    const float bo = b_out[e];
    for (int mt = 0; mt < 4; mt++) {
      const long m0 = mBase + wm + mt * 16 + quad * 4;
      for (int r = 0; r < 4; r++) {
        const long m = m0 + r;
        Out[m * DMODEL + e] = acc[mt][nt][r] + bo + X[m * DMODEL + e];
      }
    }
  }
}

// ---------------------------------------------------------------- launch
extern "C" void kernel_launch(void* const* d_in, const int* in_sizes, int n_in,
                              void* d_out, int out_size, void* d_ws, size_t ws_size,
                              hipStream_t stream) {
  const float* X     = (const float*)d_in[0];  // [8,4096,2048]
  const float* W_in  = (const float*)d_in[1];  // [6144,2048]
  const float* b_in  = (const float*)d_in[2];  // [6144]
  const float* W_out = (const float*)d_in[3];  // [2048,2048]
  const float* b_out = (const float*)d_in[4];  // [2048]
  float* Out = (float*)d_out;

  char* ws = (char*)d_ws;
  _Float16* Xh  = (_Float16*)(ws);                 // 134,217,728 B
  _Float16* W1h = (_Float16*)(ws + 134217728L);    //  25,165,824 B
  _Float16* W2h = (_Float16*)(ws + 159383552L);    //   8,388,608 B
  _Float16* QKV = (_Float16*)(ws + 167772160L);    // 402,653,184 B
  float*    A   = (float*)  (ws + 570425344L);     //      65,536 B

  k_f2h<<<65536, 256, 0, stream>>>(X,     Xh,  N_TOK * DMODEL);
  k_f2h<<<12288, 256, 0, stream>>>(W_in,  W1h, E1 * DMODEL);
  k_f2h<<< 4096, 256, 0, stream>>>(W_out, W2h, DMODEL * DMODEL);
  k_zero<<<64, 256, 0, stream>>>(A, 8 * (int)DMODEL);

  k_gemm_qkv<<<dim3(256, 48), 256, 0, stream>>>(Xh, W1h, b_in, QKV);
  k_reduce_a<<<512, 256, 0, stream>>>(QKV, A);
  k_make_y1<<<32768, 256, 0, stream>>>(QKV, A);
  k_gemm_out<<<dim3(256, 16), 256, 0, stream>>>(QKV, W2h, b_out, X, Out);
}

// Round 2
// 2187.416 us; speedup vs baseline: 1.1412x; 1.1412x over previous
//
#include <hip/hip_runtime.h>

// Problem constants: B=8, S=4096, D=2048
#define N_TOK   32768L
#define DMODEL  2048L
#define E1      6144L
#define ROT     1024
#define SMASK   4095

typedef __attribute__((ext_vector_type(8))) _Float16 half8;
typedef __attribute__((ext_vector_type(4))) _Float16 half4;
typedef __attribute__((ext_vector_type(4))) float    floatx4;
typedef __attribute__((ext_vector_type(4))) float    float4v;

// async global->LDS, 16B/lane; LDS dest = wave-uniform base + lane*16.
__device__ inline void gld16(const void* g, void* l) {
  __builtin_amdgcn_global_load_lds(
      (const __attribute__((address_space(1))) unsigned int*)g,
      (__attribute__((address_space(3))) unsigned int*)l,
      16, 0, 0);
}

// ---------------------------------------------------------------- converts
__global__ __launch_bounds__(256) void k_f2h(const float* __restrict__ in,
                                             _Float16* __restrict__ out,
                                             long nElem) {
  long i = ((long)blockIdx.x * 256 + threadIdx.x) * 4;
  if (i + 3 < nElem) {
    float4v v = *(const float4v*)(in + i);
    half4 o;
    o[0] = (_Float16)v[0]; o[1] = (_Float16)v[1];
    o[2] = (_Float16)v[2]; o[3] = (_Float16)v[3];
    *(half4*)(out + i) = o;
  }
}

__global__ __launch_bounds__(256) void k_zero(float* __restrict__ p, int n) {
  int i = blockIdx.x * 256 + threadIdx.x;
  if (i < n) p[i] = 0.f;
}

// ---------------------------------------------------------------- rope table
// tab[s][j] = (cos, sin) of angle = fp32(s) * fp32(10000^(-j/512)), j = d/2.
// Same arithmetic as round-1 inline version (double sincos of fp32 angle).
__global__ __launch_bounds__(256) void k_tab(float2* __restrict__ tab) {
  int i = blockIdx.x * 256 + threadIdx.x;   // [0, 4096*512)
  int s = i >> 9, j = i & 511;
  float invf = (float)pow(10000.0, -(double)j / 512.0);
  float ang  = (float)s * invf;
  double sd, cd; sincos((double)ang, &sd, &cd);
  float2 o; o.x = (float)cd; o.y = (float)sd;
  tab[i] = o;
}

// ---------------------------------------------------------------- GEMM1
// QKV[m][e] = sum_d Xh[m][d] * W1h[e][d] + b_in[e]
// Bank swizzle: global 16B chunk c of row r lives at LDS slot (c ^ swz(r)),
// swz(r) = (r ^ (r>>2)) & 3. Staging thread t (row t>>2, slot t&3) therefore
// fetches global chunk (t&3) ^ swz(t>>2); fragment reads slot quad ^ swz(row).
__global__ __launch_bounds__(256) void k_gemm_qkv(
    const _Float16* __restrict__ Xh, const _Float16* __restrict__ W1h,
    const float* __restrict__ b_in, _Float16* __restrict__ QKV) {
  __shared__ _Float16 As[128 * 32];
  __shared__ _Float16 Bs[128 * 32];
  const int t    = threadIdx.x;
  const int w    = t >> 6;
  const int l    = t & 63;
  const int quad = l >> 4;
  const int ln   = l & 15;
  const int wm   = (w & 1) << 6;
  const int wn   = (w >> 1) << 6;
  const int bid  = blockIdx.x;            // e-major: consecutive bids share A band
  const long mBase = (long)(bid / 48) * 128;
  const long eBase = (long)(bid % 48) * 128;
  const int r4 = t >> 2;
  const int c4 = (((t & 3) ^ ((t >> 2) & 3) ^ ((t >> 4) & 3)) << 3); // swizzled chunk, halfwords
  const int cs_off = (quad ^ (ln & 3) ^ ((ln >> 2) & 3)) << 3;       // fragment slot, halfwords

  floatx4 acc[4][4];
  for (int i = 0; i < 4; i++)
    for (int j = 0; j < 4; j++) acc[i][j] = (floatx4){0.f, 0.f, 0.f, 0.f};

  for (int k0 = 0; k0 < (int)DMODEL; k0 += 32) {
    const _Float16* gA0 = Xh  + (mBase + r4) * DMODEL + k0 + c4;
    const _Float16* gB0 = W1h + (eBase + r4) * DMODEL + k0 + c4;
    gld16(gA0,                &As[t * 8]);
    gld16(gA0 + 64 * DMODEL,  &As[2048 + t * 8]);
    gld16(gB0,                &Bs[t * 8]);
    gld16(gB0 + 64 * DMODEL,  &Bs[2048 + t * 8]);
    __builtin_amdgcn_s_waitcnt(0);
    __syncthreads();

    half8 af[4], bf[4];
    for (int mt = 0; mt < 4; mt++)
      af[mt] = *(const half8*)&As[(wm + mt * 16 + ln) * 32 + cs_off];
    for (int nt = 0; nt < 4; nt++)
      bf[nt] = *(const half8*)&Bs[(wn + nt * 16 + ln) * 32 + cs_off];
    for (int mt = 0; mt < 4; mt++)
      for (int nt = 0; nt < 4; nt++)
        acc[mt][nt] = __builtin_amdgcn_mfma_f32_16x16x32_f16(
            af[mt], bf[nt], acc[mt][nt], 0, 0, 0);
    __syncthreads();
  }

  // C/D: col = lane&15, row = quad*4 + reg
  for (int nt = 0; nt < 4; nt++) {
    const long e  = eBase + wn + nt * 16 + ln;
    const float bi = b_in[e];
    for (int mt = 0; mt < 4; mt++) {
      const long m0 = mBase + wm + mt * 16 + quad * 4;
      for (int r = 0; r < 4; r++)
        QKV[(m0 + r) * E1 + e] = (_Float16)(acc[mt][nt][r] + bi);
    }
  }
}

// ---------------------------------------------------------------- reduce A
// A[b][d] = sum_s rope(K)[b,s,d]/||rope(K)[b,s,:]|| * V[b,s,d]
__global__ __launch_bounds__(256) void k_reduce_a(
    const _Float16* __restrict__ QKV, const float2* __restrict__ tab,
    float* __restrict__ A) {
  const int t  = threadIdx.x;
  const int w  = t >> 6;
  const int l  = t & 63;
  const int wg = blockIdx.x * 4 + w;      // 0..2047
  const long row0 = (long)wg * 16;        // 16 rows per wave, same b
  const int b  = (int)(row0 >> 12);
  const int d0 = l * 32;                  // lane covers 32 contiguous d

  float acc[32];
  for (int j = 0; j < 32; j++) acc[j] = 0.f;

  for (int i = 0; i < 16; i++) {
    const long n = row0 + i;
    const int  s = (int)(n & SMASK);
    const _Float16* Kr = QKV + n * E1 + DMODEL     + d0;
    const _Float16* Vr = QKV + n * E1 + 2 * DMODEL + d0;
    float kx[32];
    for (int c = 0; c < 4; c++) {
      half8 h = *(const half8*)(Kr + c * 8);
      for (int j = 0; j < 8; j++) kx[c * 8 + j] = (float)h[j];
    }
    if (d0 < ROT) {
      const float2* trow = tab + ((long)s << 9) + (d0 >> 1);
      for (int p = 0; p < 16; p++) {
        float2 cs2 = trow[p];
        float x0 = kx[2 * p], x1 = kx[2 * p + 1];
        kx[2 * p]     = x0 * cs2.x - x1 * cs2.y;
        kx[2 * p + 1] = x1 * cs2.x + x0 * cs2.y;
      }
    }
    float ss = 0.f;
    for (int j = 0; j < 32; j++) ss += kx[j] * kx[j];
    for (int off = 32; off; off >>= 1) ss += __shfl_xor(ss, off);
    const float sc = 1.0f / fmaxf(sqrtf(ss), 1e-12f);
    for (int c = 0; c < 4; c++) {
      half8 h = *(const half8*)(Vr + c * 8);
      for (int j = 0; j < 8; j++)
        acc[c * 8 + j] += kx[c * 8 + j] * sc * (float)h[j];
    }
  }
  float* Ap = A + (long)b * DMODEL + d0;
  for (int j = 0; j < 32; j++) atomicAdd(&Ap[j], acc[j]);
}

// ---------------------------------------------------------------- Y1 = A ⊙ rope(Q), in place in Q slice
__global__ __launch_bounds__(256) void k_make_y1(
    _Float16* __restrict__ QKV, const float2* __restrict__ tab,
    const float* __restrict__ A) {
  const long idx = (long)blockIdx.x * 256 + threadIdx.x;
  const long n   = idx >> 8;
  const int  c   = (int)(idx & 255);
  const int  d   = c * 8;
  const int  b   = (int)(n >> 12);
  const int  s   = (int)(n & SMASK);
  _Float16* Qp = QKV + n * E1 + d;
  half8 h = *(half8*)Qp;
  float x[8];
  for (int j = 0; j < 8; j++) x[j] = (float)h[j];
  if (d < ROT) {
    const float2* trow = tab + ((long)s << 9) + (d >> 1);
    for (int p = 0; p < 4; p++) {
      float2 cs2 = trow[p];
      float x0 = x[2 * p], x1 = x[2 * p + 1];
      x[2 * p]     = x0 * cs2.x - x1 * cs2.y;
      x[2 * p + 1] = x1 * cs2.x + x0 * cs2.y;
    }
  }
  const float* Ap = A + (long)b * DMODEL + d;
  for (int j = 0; j < 8; j++) x[j] *= Ap[j];
  half8 o;
  for (int j = 0; j < 8; j++) o[j] = (_Float16)x[j];
  *(half8*)Qp = o;
}

// ---------------------------------------------------------------- GEMM2
// Out[m][e] = sum_d Y1[m][d] * W2h[e][d] + b_out[e] + X[m][e]
__global__ __launch_bounds__(256) void k_gemm_out(
    const _Float16* __restrict__ Y1,   // QKV base, row stride E1, cols [0,2048)
    const _Float16* __restrict__ W2h,
    const float* __restrict__ b_out, const float* __restrict__ X,
    float* __restrict__ Out) {
  __shared__ _Float16 As[128 * 32];
  __shared__ _Float16 Bs[128 * 32];
  const int t    = threadIdx.x;
  const int w    = t >> 6;
  const int l    = t & 63;
  const int quad = l >> 4;
  const int ln   = l & 15;
  const int wm   = (w & 1) << 6;
  const int wn   = (w >> 1) << 6;
  const int bid  = blockIdx.x;            // e-major remap
  const long mBase = (long)(bid >> 4) * 128;
  const long eBase = (long)(bid & 15) * 128;
  const int r4 = t >> 2;
  const int c4 = (((t & 3) ^ ((t >> 2) & 3) ^ ((t >> 4) & 3)) << 3);
  const int cs_off = (quad ^ (ln & 3) ^ ((ln >> 2) & 3)) << 3;

  floatx4 acc[4][4];
  for (int i = 0; i < 4; i++)
    for (int j = 0; j < 4; j++) acc[i][j] = (floatx4){0.f, 0.f, 0.f, 0.f};

  for (int k0 = 0; k0 < (int)DMODEL; k0 += 32) {
    const _Float16* gA0 = Y1  + (mBase + r4) * E1     + k0 + c4;
    const _Float16* gB0 = W2h + (eBase + r4) * DMODEL + k0 + c4;
    gld16(gA0,               &As[t * 8]);
    gld16(gA0 + 64 * E1,     &As[2048 + t * 8]);
    gld16(gB0,               &Bs[t * 8]);
    gld16(gB0 + 64 * DMODEL, &Bs[2048 + t * 8]);
    __builtin_amdgcn_s_waitcnt(0);
    __syncthreads();

    half8 af[4], bf[4];
    for (int mt = 0; mt < 4; mt++)
      af[mt] = *(const half8*)&As[(wm + mt * 16 + ln) * 32 + cs_off];
    for (int nt = 0; nt < 4; nt++)
      bf[nt] = *(const half8*)&Bs[(wn + nt * 16 + ln) * 32 + cs_off];
    for (int mt = 0; mt < 4; mt++)
      for (int nt = 0; nt < 4; nt++)
        acc[mt][nt] = __builtin_amdgcn_mfma_f32_16x16x32_f16(
            af[mt], bf[nt], acc[mt][nt], 0, 0, 0);
    __syncthreads();
  }

  for (int nt = 0; nt < 4; nt++) {
    const long e = eBase + wn + nt * 16 + ln;
    const float bo = b_out[e];
    for (int mt = 0; mt < 4; mt++) {
      const long m0 = mBase + wm + mt * 16 + quad * 4;
      for (int r = 0; r < 4; r++) {
        const long m = m0 + r;
        Out[m * DMODEL + e] = acc[mt][nt][r] + bo + X[m * DMODEL + e];
      }
    }
  }
}

// ---------------------------------------------------------------- launch
extern "C" void kernel_launch(void* const* d_in, const int* in_sizes, int n_in,
                              void* d_out, int out_size, void* d_ws, size_t ws_size,
                              hipStream_t stream) {
  const float* X     = (const float*)d_in[0];  // [8,4096,2048]
  const float* W_in  = (const float*)d_in[1];  // [6144,2048]
  const float* b_in  = (const float*)d_in[2];  // [6144]
  const float* W_out = (const float*)d_in[3];  // [2048,2048]
  const float* b_out = (const float*)d_in[4];  // [2048]
  float* Out = (float*)d_out;

  char* ws = (char*)d_ws;
  _Float16* Xh  = (_Float16*)(ws);                 // 134,217,728 B (dead after GEMM1)
  _Float16* W1h = (_Float16*)(ws + 134217728L);    //  25,165,824 B
  _Float16* W2h = (_Float16*)(ws + 159383552L);    //   8,388,608 B
  _Float16* QKV = (_Float16*)(ws + 167772160L);    // 402,653,184 B
  float*    A   = (float*)  (ws + 570425344L);     //      65,536 B
  float2*   TAB = (float2*)(ws);                   // 16,777,216 B, reuses Xh slot

  k_f2h<<<65536, 256, 0, stream>>>(X,     Xh,  N_TOK * DMODEL);
  k_f2h<<<12288, 256, 0, stream>>>(W_in,  W1h, E1 * DMODEL);
  k_f2h<<< 4096, 256, 0, stream>>>(W_out, W2h, DMODEL * DMODEL);
  k_zero<<<64, 256, 0, stream>>>(A, 8 * (int)DMODEL);

  k_gemm_qkv<<<12288, 256, 0, stream>>>(Xh, W1h, b_in, QKV);
  k_tab<<<8192, 256, 0, stream>>>(TAB);            // overwrites Xh (now dead)
  k_reduce_a<<<512, 256, 0, stream>>>(QKV, TAB, A);
  k_make_y1<<<32768, 256, 0, stream>>>(QKV, TAB, A);
  k_gemm_out<<<4096, 256, 0, stream>>>(QKV, W2h, b_out, X, Out);
}